// Round 12
// baseline (252.795 us; speedup 1.0000x reference)
//
#include <hip/hip_runtime.h>
#include <hip/hip_bf16.h>
#include <math.h>

#define NPTS 100000
#define NSTRIPE 1568     // 64-row stripes; 196 per XCD
#define KCOMP 64

typedef float v4f __attribute__((ext_vector_type(4)));
typedef float v2f __attribute__((ext_vector_type(2)));
typedef __bf16 v8bf __attribute__((ext_vector_type(8)));
typedef __bf16 v4bf __attribute__((ext_vector_type(4)));

// Fragment-native layouts (NO LDS, NO barriers in the GEMM):
//   Xb[st(1568)][ks(8)][m(4)][lane(64)][e(8)] : X[st*64 + m*16 + (l&15)][ks*32 + (l>>4)*8 + e]
//   Bt[cw(16)][ks(8)][n(4)][lane(64)][e(8)]   : B[cw*64 + n*16 + (l&15)][ks*32 + (l>>4)*8 + e]
// Every fragment load = one coalesced global_load_dwordx4 (base + lane*16).
// A stripe = 32 KB bf16 -> L1-resident across the wave's 8 cw iterations.

// ---------- kernel 1: per-component prep (Cholesky of I+M^T M, B = L^-1 M^T) ----------
__global__ __launch_bounds__(256) void prep_comp(const float* __restrict__ M,
                                                 const float* __restrict__ pi,
                                                 __bf16* __restrict__ Bt,
                                                 float* __restrict__ cvec,
                                                 float logSA) {
    __shared__ float Ml[256][16];
    __shared__ float S[16][17];
    __shared__ float sh_logpi;
    const int k = blockIdx.x, t = threadIdx.x;

    const float4* src = (const float4*)(M + (size_t)k * 4096 + (size_t)t * 16);
    float4 a0 = src[0], a1 = src[1], a2 = src[2], a3 = src[3];
    ((float4*)Ml[t])[0] = a0; ((float4*)Ml[t])[1] = a1;
    ((float4*)Ml[t])[2] = a2; ((float4*)Ml[t])[3] = a3;

    if (t < 64) {
        float v = pi[t];
        float mx = v;
        for (int off = 32; off; off >>= 1) mx = fmaxf(mx, __shfl_xor(mx, off));
        float e = __expf(v - mx);
        float s = e;
        for (int off = 32; off; off >>= 1) s += __shfl_xor(s, off);
        if (t == 0) sh_logpi = pi[k] - mx - logf(s);
    }
    __syncthreads();

    {
        int r = t >> 4, c = t & 15;
        float s = (r == c) ? 1.0f : 0.0f;
        for (int p = 0; p < 256; ++p) s += Ml[p][r] * Ml[p][c];
        S[r][c] = s;
    }
    __syncthreads();

    for (int j = 0; j < 16; ++j) {
        if (t == 0) S[j][j] = sqrtf(S[j][j]);
        __syncthreads();
        if (t > j && t < 16) S[t][j] = S[t][j] / S[j][j];
        __syncthreads();
        {
            int r = t >> 4, c = t & 15;
            if (r > j && c > j && c <= r) S[r][c] -= S[r][j] * S[c][j];
        }
        __syncthreads();
    }

    if (t == 0) {
        float ldet = 0.0f;
        for (int j = 0; j < 16; ++j) ldet += logf(S[j][j]);
        cvec[k] = logSA - ldet + sh_logpi;
    }

    float m[16] = {a0.x, a0.y, a0.z, a0.w, a1.x, a1.y, a1.z, a1.w,
                   a2.x, a2.y, a2.z, a2.w, a3.x, a3.y, a3.z, a3.w};
    float y[16];
#pragma unroll
    for (int r = 0; r < 16; ++r) {
        float v = m[r];
#pragma unroll
        for (int q = 0; q < r; ++q) v -= S[r][q] * y[q];
        y[r] = v / S[r][r];
    }
    // fragment-native Bt write: cw=k>>2, n=k&3, lane=((t>>3)&3)*16+r, ks=t>>5, e=t&7
    const int cw = k >> 2, n = k & 3;
    const int ks = t >> 5, e = t & 7;
    const int lbase = ((t >> 3) & 3) * 16;
#pragma unroll
    for (int r = 0; r < 16; ++r) {
        const size_t off = (size_t)cw * 16384 + (size_t)ks * 2048 + (size_t)n * 512
                         + (size_t)(lbase + r) * 8 + e;
        Bt[off] = (__bf16)y[r];
    }
}

// ---------- kernel 2: X fp32 -> bf16 into fragment-native stripes ----------
__global__ __launch_bounds__(256) void convert_X(const float* __restrict__ X,
                                                 __bf16* __restrict__ Xb) {
    __shared__ __bf16 T[64][264];
    const int st = blockIdx.x;
    const int n0 = st * 64;
    const int t = threadIdx.x;

#pragma unroll
    for (int j = 0; j < 16; ++j) {
        const int u = j * 256 + t;
        const int r = u >> 6, c4 = u & 63;
        const int n = n0 + r;
        float4 v = make_float4(0.f, 0.f, 0.f, 0.f);
        if (n < NPTS) v = ((const float4*)X)[(size_t)n * 64 + c4];
        v4bf o = {(__bf16)v.x, (__bf16)v.y, (__bf16)v.z, (__bf16)v.w};
        *(v4bf*)&T[r][c4 * 4] = o;
    }
    __syncthreads();

#pragma unroll
    for (int ks = 0; ks < 8; ++ks) {
        const int mh = t >> 6;
        const int l = t & 63;
        const int row = mh * 16 + (l & 15);
        const int col = ks * 32 + (l >> 4) * 8;
        v8bf val = *(const v8bf*)&T[row][col];
        const size_t off = (size_t)st * 16384 + (size_t)ks * 2048
                         + (size_t)mh * 512 + (size_t)l * 8;
        *(v8bf*)(Xb + off) = val;
    }
}

// ---------- kernel 3: barrier-free GEMM + fused density + partial online-LSE ----------
// 3136 wave-jobs: (stripe, half). Each wave: 64 rows x 8 cw-groups (32 comps).
// A remat from L1 (32 KB stripe); B ring-prefetched from L2. Writes per-point
// partial (m, s) to pairs[pt][half]. VGPR capped at 128 -> 4 waves/SIMD.
__global__ __launch_bounds__(256, 4) void gemm_density(const __bf16* __restrict__ Xb,
                                                       const __bf16* __restrict__ Bt,
                                                       const float* __restrict__ cvec,
                                                       float* __restrict__ pairs) {
    const int bid = blockIdx.x;                 // 784 blocks
    const int xcd = bid & 7, i = bid >> 3;      // i: 0..97
    const int w = threadIdx.x >> 6, lane = threadIdx.x & 63;
    const int st = xcd * 196 + i * 2 + (w >> 1);   // waves 0,1 share a stripe
    const int h = w & 1;                            // cw half: 0..1
    const int cw0 = h * 8;
    const int lo = lane & 15;
    const int n0 = st * 64;

    const __bf16* Ab = Xb + ((size_t)st << 14) + lane * 8;
    const __bf16* Bb = Bt + lane * 8;

#define LOADB(dst, cw_, ks_) do {                                          \
    const __bf16* _p = Bb + ((size_t)(cw_) << 14) + ((size_t)(ks_) << 11); \
    dst[0] = *(const v8bf*)(_p);                                           \
    dst[1] = *(const v8bf*)(_p + 512);                                     \
    dst[2] = *(const v8bf*)(_p + 1024);                                    \
    dst[3] = *(const v8bf*)(_p + 1536);                                    \
} while (0)

    v8bf bg[4][4];          // period-4 ring, depth-2 prefetch; static reg indices
    LOADB(bg[0], cw0, 0);
    LOADB(bg[1], cw0, 1);

    float mrun[4] = {-INFINITY, -INFINITY, -INFINITY, -INFINITY};
    float srun[4] = {0.f, 0.f, 0.f, 0.f};
    const float4* cv4 = (const float4*)cvec;

#pragma unroll 1
    for (int c = 0; c < 8; ++c) {
        const int cw = cw0 + c;
        v4f acc[4][4] = {};
#pragma unroll
        for (int ks = 0; ks < 8; ++ks) {
            const int pk = ks + 2;
            const int pcw = (pk < 8) ? cw : (cw0 + ((c + 1) & 7));
            LOADB(bg[pk & 3], pcw, pk & 7);
            v8bf af[4];
#pragma unroll
            for (int m = 0; m < 4; ++m)
                af[m] = *(const v8bf*)(Ab + ks * 2048 + m * 512);
#pragma unroll
            for (int m = 0; m < 4; ++m)
#pragma unroll
                for (int n = 0; n < 4; ++n)
                    acc[m][n] = __builtin_amdgcn_mfma_f32_16x16x32_bf16(
                        bg[ks & 3][n], af[m], acc[m][n], 0, 0, 0);
        }

        const float4 cv = cv4[cw];
#pragma unroll
        for (int m = 0; m < 4; ++m) {
            float d[4];
#pragma unroll
            for (int n = 0; n < 4; ++n) {
                v4f qv = acc[m][n];
                float s = qv[0] * qv[0] + qv[1] * qv[1] + qv[2] * qv[2] + qv[3] * qv[3];
                s += __shfl_xor(s, 16);
                s += __shfl_xor(s, 32);
                const float cc = (n == 0) ? cv.x : (n == 1) ? cv.y : (n == 2) ? cv.z : cv.w;
                d[n] = cc - 128.0f * __logf(1.0f - s);
            }
            const float mt = fmaxf(fmaxf(d[0], d[1]), fmaxf(d[2], d[3]));
            const float mn = fmaxf(mrun[m], mt);
            srun[m] = srun[m] * __expf(mrun[m] - mn)
                    + __expf(d[0] - mn) + __expf(d[1] - mn)
                    + __expf(d[2] - mn) + __expf(d[3] - mn);
            mrun[m] = mn;
        }
    }
#undef LOADB

    // ---- write partial (m, s) per point for this half ----
    if (lane < 16) {
#pragma unroll
        for (int m = 0; m < 4; ++m) {
            const int pt = n0 + m * 16 + lo;
            v2f p; p[0] = mrun[m]; p[1] = srun[m];
            *(v2f*)(pairs + (size_t)pt * 4 + h * 2) = p;
        }
    }
}

// ---------- kernel 4: merge two halves -> per-point LSE -> global sum ----------
__global__ __launch_bounds__(256) void merge_ll(const float* __restrict__ pairs,
                                                float* __restrict__ out) {
    const int n = blockIdx.x * 256 + threadIdx.x;
    float local = 0.0f;
    if (n < NPTS) {
        const float4 p = *(const float4*)(pairs + (size_t)n * 4);
        const float M = fmaxf(p.x, p.z);
        local = M + __logf(p.y * __expf(p.x - M) + p.w * __expf(p.z - M));
    }
    for (int off = 32; off; off >>= 1) local += __shfl_down(local, off);
    __shared__ float part[4];
    const int wv = threadIdx.x >> 6, lane = threadIdx.x & 63;
    if (lane == 0) part[wv] = local;
    __syncthreads();
    if (threadIdx.x == 0) atomicAdd(out, part[0] + part[1] + part[2] + part[3]);
}

extern "C" void kernel_launch(void* const* d_in, const int* in_sizes, int n_in,
                              void* d_out, int out_size, void* d_ws, size_t ws_size,
                              hipStream_t stream) {
    const float* X  = (const float*)d_in[0];
    const float* M  = (const float*)d_in[1];
    const float* pi = (const float*)d_in[2];
    float* out = (float*)d_out;

    char* ws = (char*)d_ws;
    __bf16* Xb    = (__bf16*)ws;                          // 1568*16384*2 = 51,380,224
    __bf16* Bt    = (__bf16*)(ws + 51380224);             // 16*16384*2   =    524,288
    float*  cvec  = (float*)(ws + 51904512);              // 256 B
    float*  pairs = (float*)(ws + 51905024);              // 100352*4*4   =  1,605,632

    const double half_p = 128.0;
    const float logSA = (float)(lgamma(half_p) - log(2.0) - half_p * log(M_PI));

    hipMemsetAsync(d_out, 0, sizeof(float), stream);
    prep_comp<<<64, 256, 0, stream>>>(M, pi, Bt, cvec, logSA);
    convert_X<<<1568, 256, 0, stream>>>(X, Xb);
    gemm_density<<<784, 256, 0, stream>>>(Xb, Bt, cvec, pairs);   // 3136 wave-jobs
    merge_ll<<<392, 256, 0, stream>>>(pairs, out);
}

// Round 13
// 209.057 us; speedup vs baseline: 1.2092x; 1.2092x over previous
//
#include <hip/hip_runtime.h>
#include <hip/hip_bf16.h>
#include <math.h>

#define NPTS 100000
#define NSTRIPE 1568     // 64-row stripes cover 100352 rows
#define KCOMP 64

typedef float v4f __attribute__((ext_vector_type(4)));
typedef __bf16 v8bf __attribute__((ext_vector_type(8)));

// Bt fragment-native: Bt[cw(16)][ks(8)][n(4)][lane(64)][e(8)]
//   = B[cw*64 + n*16 + (l&15)][ks*32 + (l>>4)*8 + e]     (bf16)
// LDS A-stripe same form: As[ks(8)][m(4)][lane(64)][e(8)] -> ds_read_b128 at
// lane*16B: linear 1KB per wave-instr, 0 bank conflicts.

// ---------- kernel 1: per-component prep (Cholesky of I+M^T M, B = L^-1 M^T) ----------
__global__ __launch_bounds__(256) void prep_comp(const float* __restrict__ M,
                                                 const float* __restrict__ pi,
                                                 __bf16* __restrict__ Bt,
                                                 float* __restrict__ cvec,
                                                 float logSA) {
    __shared__ float Ml[256][16];
    __shared__ float S[16][17];
    __shared__ float sh_logpi;
    const int k = blockIdx.x, t = threadIdx.x;

    const float4* src = (const float4*)(M + (size_t)k * 4096 + (size_t)t * 16);
    float4 a0 = src[0], a1 = src[1], a2 = src[2], a3 = src[3];
    ((float4*)Ml[t])[0] = a0; ((float4*)Ml[t])[1] = a1;
    ((float4*)Ml[t])[2] = a2; ((float4*)Ml[t])[3] = a3;

    if (t < 64) {
        float v = pi[t];
        float mx = v;
        for (int off = 32; off; off >>= 1) mx = fmaxf(mx, __shfl_xor(mx, off));
        float e = __expf(v - mx);
        float s = e;
        for (int off = 32; off; off >>= 1) s += __shfl_xor(s, off);
        if (t == 0) sh_logpi = pi[k] - mx - logf(s);
    }
    __syncthreads();

    {
        int r = t >> 4, c = t & 15;
        float s = (r == c) ? 1.0f : 0.0f;
        for (int p = 0; p < 256; ++p) s += Ml[p][r] * Ml[p][c];
        S[r][c] = s;
    }
    __syncthreads();

    for (int j = 0; j < 16; ++j) {
        if (t == 0) S[j][j] = sqrtf(S[j][j]);
        __syncthreads();
        if (t > j && t < 16) S[t][j] = S[t][j] / S[j][j];
        __syncthreads();
        {
            int r = t >> 4, c = t & 15;
            if (r > j && c > j && c <= r) S[r][c] -= S[r][j] * S[c][j];
        }
        __syncthreads();
    }

    if (t == 0) {
        float ldet = 0.0f;
        for (int j = 0; j < 16; ++j) ldet += logf(S[j][j]);
        cvec[k] = logSA - ldet + sh_logpi;
    }

    float m[16] = {a0.x, a0.y, a0.z, a0.w, a1.x, a1.y, a1.z, a1.w,
                   a2.x, a2.y, a2.z, a2.w, a3.x, a3.y, a3.z, a3.w};
    float y[16];
#pragma unroll
    for (int r = 0; r < 16; ++r) {
        float v = m[r];
#pragma unroll
        for (int q = 0; q < r; ++q) v -= S[r][q] * y[q];
        y[r] = v / S[r][r];
    }
    // fragment-native Bt write: cw=k>>2, n=k&3, lane=((t>>3)&3)*16+r, ks=t>>5, e=t&7
    const int cw = k >> 2, n = k & 3;
    const int ks = t >> 5, e = t & 7;
    const int lbase = ((t >> 3) & 3) * 16;
#pragma unroll
    for (int r = 0; r < 16; ++r) {
        const size_t off = (size_t)cw * 16384 + (size_t)ks * 2048 + (size_t)n * 512
                         + (size_t)(lbase + r) * 8 + e;
        Bt[off] = (__bf16)y[r];
    }
}

// ---------- kernel 2: fused convert + GEMM + density + logsumexp ----------
// Block (4 waves) owns a 64-row stripe. Stage fp32 X -> bf16 fragment LDS once;
// wave w computes cw in [4w,4w+4) with A from LDS (read-only, no inner barriers),
// B double-buffered from L2. Per-wave online LSE -> LDS -> one atomicAdd/block.
__global__ __launch_bounds__(256, 3) void gemm_density(const float* __restrict__ X,
                                                       const __bf16* __restrict__ Bt,
                                                       const float* __restrict__ cvec,
                                                       float* __restrict__ out) {
    __shared__ __bf16 As[16384];          // 32 KB: [ks(8)][m(4)][lane(64)][e(8)]
    __shared__ float psum[4][4][16][2];   // 2 KB: [wave][m][lo][m,s]
    const int st = blockIdx.x;
    const int t = threadIdx.x;
    const int w = t >> 6, lane = t & 63;
    const int lo = lane & 15;
    const int n0 = st * 64;

    // ---- staging: fp32 -> bf16 -> fragment-native LDS (fused convert) ----
    {
        const int rowl = t >> 2;             // 0..63
        const int cb = (t & 3) << 6;         // 0,64,128,192
        const int n = n0 + rowl;
        const bool valid = n < NPTS;
        const float* xp = X + (size_t)n * 256 + cb;
        const int m_ = rowl >> 4;
        const int lr = rowl & 15;
#pragma unroll
        for (int j = 0; j < 8; ++j) {
            float4 f0 = make_float4(0.f, 0.f, 0.f, 0.f), f1 = f0;
            if (valid) {
                f0 = *(const float4*)(xp + j * 8);
                f1 = *(const float4*)(xp + j * 8 + 4);
            }
            v8bf v;
            v[0] = (__bf16)f0.x; v[1] = (__bf16)f0.y; v[2] = (__bf16)f0.z; v[3] = (__bf16)f0.w;
            v[4] = (__bf16)f1.x; v[5] = (__bf16)f1.y; v[6] = (__bf16)f1.z; v[7] = (__bf16)f1.w;
            const int k = cb + j * 8;
            const int ks = k >> 5, sub = (k >> 3) & 3;
            const int idx = ks * 2048 + m_ * 512 + (lr + (sub << 4)) * 8;
            *(v8bf*)&As[idx] = v;            // ds_write_b128, 2-way (free)
        }
    }
    __syncthreads();                          // the ONLY barrier before merge

    // ---- per-wave GEMM over cw = 4w .. 4w+3 ----
    const __bf16* Bb = Bt + lane * 8;
#define LOADB(dst, cw_, ks_) do {                                          \
    const __bf16* _p = Bb + ((size_t)(cw_) << 14) + ((size_t)(ks_) << 11); \
    dst[0] = *(const v8bf*)(_p);                                           \
    dst[1] = *(const v8bf*)(_p + 512);                                     \
    dst[2] = *(const v8bf*)(_p + 1024);                                    \
    dst[3] = *(const v8bf*)(_p + 1536);                                    \
} while (0)
#define RDA(af, ks) do {                                                   \
    _Pragma("unroll")                                                      \
    for (int m = 0; m < 4; ++m)                                            \
        af[m] = *(const v8bf*)&As[(ks) * 2048 + m * 512 + lane * 8];       \
} while (0)
#define MFMA16(bg, af) do {                                                \
    _Pragma("unroll")                                                      \
    for (int m = 0; m < 4; ++m)                                            \
        _Pragma("unroll")                                                  \
        for (int n = 0; n < 4; ++n)                                        \
            acc[m][n] = __builtin_amdgcn_mfma_f32_16x16x32_bf16(           \
                bg[n], af[m], acc[m][n], 0, 0, 0);                         \
} while (0)

    const int cw0 = w << 2;
    v8bf bg0[4], bg1[4];
    LOADB(bg0, cw0, 0);

    float mrun[4] = {-INFINITY, -INFINITY, -INFINITY, -INFINITY};
    float srun[4] = {0.f, 0.f, 0.f, 0.f};
    const float4* cv4 = (const float4*)cvec;

#pragma unroll 1
    for (int c = 0; c < 4; ++c) {
        const int cw = cw0 + c;
        const int cwn = cw0 + ((c + 1) & 3);      // wraps on last c (harmless reload)
        v4f acc[4][4] = {};
#pragma unroll
        for (int ks2 = 0; ks2 < 4; ++ks2) {
            const int ks = ks2 * 2;
            v8bf af0[4], af1[4];
            LOADB(bg1, cw, ks + 1);               // prefetch odd group
            RDA(af0, ks);
            MFMA16(bg0, af0);
            if (ks + 2 < 8) LOADB(bg0, cw, ks + 2);   // prefetch next even group
            else            LOADB(bg0, cwn, 0);       // next cw's group 0
            RDA(af1, ks + 1);
            MFMA16(bg1, af1);
        }

        // ---- epilogue: quad -> density -> online LSE ----
        const float4 cv = cv4[cw];
#pragma unroll
        for (int m = 0; m < 4; ++m) {
            float d[4];
#pragma unroll
            for (int n = 0; n < 4; ++n) {
                v4f qv = acc[m][n];
                float s = qv[0] * qv[0] + qv[1] * qv[1] + qv[2] * qv[2] + qv[3] * qv[3];
                s += __shfl_xor(s, 16);
                s += __shfl_xor(s, 32);
                const float cc = (n == 0) ? cv.x : (n == 1) ? cv.y : (n == 2) ? cv.z : cv.w;
                d[n] = cc - 128.0f * __logf(1.0f - s);
            }
            const float mt = fmaxf(fmaxf(d[0], d[1]), fmaxf(d[2], d[3]));
            const float mn = fmaxf(mrun[m], mt);
            srun[m] = srun[m] * __expf(mrun[m] - mn)
                    + __expf(d[0] - mn) + __expf(d[1] - mn)
                    + __expf(d[2] - mn) + __expf(d[3] - mn);
            mrun[m] = mn;
        }
    }
#undef LOADB
#undef RDA
#undef MFMA16

    // ---- merge 4 per-wave partials -> per-point LSE -> one atomic ----
    if (lane < 16) {
#pragma unroll
        for (int m = 0; m < 4; ++m) {
            psum[w][m][lo][0] = mrun[m];
            psum[w][m][lo][1] = srun[m];
        }
    }
    __syncthreads();
    if (t < 64) {
        const int m = t >> 4, l = t & 15;
        float M0 = psum[0][m][l][0];
        M0 = fmaxf(M0, psum[1][m][l][0]);
        M0 = fmaxf(M0, psum[2][m][l][0]);
        M0 = fmaxf(M0, psum[3][m][l][0]);
        float s = psum[0][m][l][1] * __expf(psum[0][m][l][0] - M0)
                + psum[1][m][l][1] * __expf(psum[1][m][l][0] - M0)
                + psum[2][m][l][1] * __expf(psum[2][m][l][0] - M0)
                + psum[3][m][l][1] * __expf(psum[3][m][l][0] - M0);
        const int pt = n0 + m * 16 + l;
        float local = (pt < NPTS) ? (M0 + __logf(s)) : 0.f;
        for (int off = 32; off; off >>= 1) local += __shfl_xor(local, off);
        if (t == 0) atomicAdd(out, local);
    }
}

extern "C" void kernel_launch(void* const* d_in, const int* in_sizes, int n_in,
                              void* d_out, int out_size, void* d_ws, size_t ws_size,
                              hipStream_t stream) {
    const float* X  = (const float*)d_in[0];
    const float* M  = (const float*)d_in[1];
    const float* pi = (const float*)d_in[2];
    float* out = (float*)d_out;

    char* ws = (char*)d_ws;
    __bf16* Bt   = (__bf16*)ws;              // 16*16384*2 = 524,288 B
    float*  cvec = (float*)(ws + 524288);    // 256 B

    const double half_p = 128.0;
    const float logSA = (float)(lgamma(half_p) - log(2.0) - half_p * log(M_PI));

    hipMemsetAsync(d_out, 0, sizeof(float), stream);
    prep_comp<<<64, 256, 0, stream>>>(M, pi, Bt, cvec, logSA);
    gemm_density<<<NSTRIPE, 256, 0, stream>>>(X, Bt, cvec, out);
}

// Round 14
// 122.085 us; speedup vs baseline: 2.0707x; 1.7124x over previous
//
#include <hip/hip_runtime.h>
#include <hip/hip_bf16.h>
#include <math.h>

#define NPTS 100000
#define NSTRIPE 1568     // 64-row stripes; 196 per XCD
#define KCOMP 64

typedef float v4f __attribute__((ext_vector_type(4)));
typedef __bf16 v8bf __attribute__((ext_vector_type(8)));
typedef __bf16 v4bf __attribute__((ext_vector_type(4)));

// Fragment-native layouts (NO LDS staging, NO barriers in the GEMM loop):
//   Xb[st(1568)][ks(8)][m(4)][lane(64)][e(8)] : X[st*64 + m*16 + (l&15)][ks*32 + (l>>4)*8 + e]
//   Bt[cw(16)][ks(8)][n(4)][lane(64)][e(8)]   : B[cw*64 + n*16 + (l&15)][ks*32 + (l>>4)*8 + e]
// Every fragment load = one coalesced global_load_dwordx4 (base + lane*16).
// Block = stripe: 4 waves share the 32 KB A-stripe (L1/L2), each covers 4 cw.

// ---------- kernel 1: per-component prep (Cholesky of I+M^T M, B = L^-1 M^T) ----------
__global__ __launch_bounds__(256) void prep_comp(const float* __restrict__ M,
                                                 const float* __restrict__ pi,
                                                 __bf16* __restrict__ Bt,
                                                 float* __restrict__ cvec,
                                                 float logSA) {
    __shared__ float Ml[256][16];
    __shared__ float S[16][17];
    __shared__ float sh_logpi;
    const int k = blockIdx.x, t = threadIdx.x;

    const float4* src = (const float4*)(M + (size_t)k * 4096 + (size_t)t * 16);
    float4 a0 = src[0], a1 = src[1], a2 = src[2], a3 = src[3];
    ((float4*)Ml[t])[0] = a0; ((float4*)Ml[t])[1] = a1;
    ((float4*)Ml[t])[2] = a2; ((float4*)Ml[t])[3] = a3;

    if (t < 64) {
        float v = pi[t];
        float mx = v;
        for (int off = 32; off; off >>= 1) mx = fmaxf(mx, __shfl_xor(mx, off));
        float e = __expf(v - mx);
        float s = e;
        for (int off = 32; off; off >>= 1) s += __shfl_xor(s, off);
        if (t == 0) sh_logpi = pi[k] - mx - logf(s);
    }
    __syncthreads();

    {
        int r = t >> 4, c = t & 15;
        float s = (r == c) ? 1.0f : 0.0f;
        for (int p = 0; p < 256; ++p) s += Ml[p][r] * Ml[p][c];
        S[r][c] = s;
    }
    __syncthreads();

    for (int j = 0; j < 16; ++j) {
        if (t == 0) S[j][j] = sqrtf(S[j][j]);
        __syncthreads();
        if (t > j && t < 16) S[t][j] = S[t][j] / S[j][j];
        __syncthreads();
        {
            int r = t >> 4, c = t & 15;
            if (r > j && c > j && c <= r) S[r][c] -= S[r][j] * S[c][j];
        }
        __syncthreads();
    }

    if (t == 0) {
        float ldet = 0.0f;
        for (int j = 0; j < 16; ++j) ldet += logf(S[j][j]);
        cvec[k] = logSA - ldet + sh_logpi;
    }

    float m[16] = {a0.x, a0.y, a0.z, a0.w, a1.x, a1.y, a1.z, a1.w,
                   a2.x, a2.y, a2.z, a2.w, a3.x, a3.y, a3.z, a3.w};
    float y[16];
#pragma unroll
    for (int r = 0; r < 16; ++r) {
        float v = m[r];
#pragma unroll
        for (int q = 0; q < r; ++q) v -= S[r][q] * y[q];
        y[r] = v / S[r][r];
    }
    // fragment-native Bt write: cw=k>>2, n=k&3, lane=((t>>3)&3)*16+r, ks=t>>5, e=t&7
    const int cw = k >> 2, n = k & 3;
    const int ks = t >> 5, e = t & 7;
    const int lbase = ((t >> 3) & 3) * 16;
#pragma unroll
    for (int r = 0; r < 16; ++r) {
        const size_t off = (size_t)cw * 16384 + (size_t)ks * 2048 + (size_t)n * 512
                         + (size_t)(lbase + r) * 8 + e;
        Bt[off] = (__bf16)y[r];
    }
}

// ---------- kernel 2: X fp32 -> bf16 into fragment-native stripes ----------
__global__ __launch_bounds__(256) void convert_X(const float* __restrict__ X,
                                                 __bf16* __restrict__ Xb) {
    __shared__ __bf16 T[64][264];
    const int st = blockIdx.x;
    const int n0 = st * 64;
    const int t = threadIdx.x;

#pragma unroll
    for (int j = 0; j < 16; ++j) {
        const int u = j * 256 + t;
        const int r = u >> 6, c4 = u & 63;
        const int n = n0 + r;
        float4 v = make_float4(0.f, 0.f, 0.f, 0.f);
        if (n < NPTS) v = ((const float4*)X)[(size_t)n * 64 + c4];
        v4bf o = {(__bf16)v.x, (__bf16)v.y, (__bf16)v.z, (__bf16)v.w};
        *(v4bf*)&T[r][c4 * 4] = o;
    }
    __syncthreads();

#pragma unroll
    for (int ks = 0; ks < 8; ++ks) {
        const int mh = t >> 6;
        const int l = t & 63;
        const int row = mh * 16 + (l & 15);
        const int col = ks * 32 + (l >> 4) * 8;
        v8bf val = *(const v8bf*)&T[row][col];
        const size_t off = (size_t)st * 16384 + (size_t)ks * 2048
                         + (size_t)mh * 512 + (size_t)l * 8;
        *(v8bf*)(Xb + off) = val;
    }
}

// ---------- kernel 3: GEMM + fused density + logsumexp ----------
// Block = stripe. Wave w covers cw in [4w, 4w+4) with R8's exact inner loop
// (fragment loads from L1/L2, depth-2 B ring, swapped-operand MFMA, no barriers).
// Online LSE across the wave's 4 cw; 4-wave LDS merge; one atomicAdd per block.
__global__ __launch_bounds__(256, 2) void gemm_density(const __bf16* __restrict__ Xb,
                                                       const __bf16* __restrict__ Bt,
                                                       const float* __restrict__ cvec,
                                                       float* __restrict__ out) {
    __shared__ float psum[4][4][16][2];   // [wave][m][lo][m,s]
    const int bid = blockIdx.x;
    const int xcd = bid & 7, i = bid >> 3;       // i: 0..195
    const int st = xcd * 196 + i;                // consecutive blocks on an XCD -> consecutive stripes
    const int t = threadIdx.x;
    const int w = t >> 6, lane = t & 63;
    const int lo = lane & 15;
    const int n0 = st * 64;
    const int cw0 = w << 2;

    const __bf16* Ab = Xb + ((size_t)st << 14) + lane * 8;
    const __bf16* Bb = Bt + lane * 8;

#define LOADB(dst, cw_, ks_) do {                                          \
    const __bf16* _p = Bb + ((size_t)(cw_) << 14) + ((size_t)(ks_) << 11); \
    dst[0] = *(const v8bf*)(_p);                                           \
    dst[1] = *(const v8bf*)(_p + 512);                                     \
    dst[2] = *(const v8bf*)(_p + 1024);                                    \
    dst[3] = *(const v8bf*)(_p + 1536);                                    \
} while (0)

    v8bf bg[4][4];          // period-4 ring, depth-2 prefetch; static indices
    LOADB(bg[0], cw0, 0);
    LOADB(bg[1], cw0, 1);

    float mrun[4] = {-INFINITY, -INFINITY, -INFINITY, -INFINITY};
    float srun[4] = {0.f, 0.f, 0.f, 0.f};
    const float4* cv4 = (const float4*)cvec;

#pragma unroll 1
    for (int c = 0; c < 4; ++c) {
        const int cw = cw0 + c;
        const int cwn = cw0 + ((c + 1) & 3);     // wraps on last c (harmless reload)
        v4f acc[4][4] = {};
#pragma unroll
        for (int ks = 0; ks < 8; ++ks) {
            const int pk = ks + 2;
            const int pcw = (pk < 8) ? cw : cwn;
            LOADB(bg[pk & 3], pcw, pk & 7);
            v8bf af[4];
#pragma unroll
            for (int m = 0; m < 4; ++m)
                af[m] = *(const v8bf*)(Ab + ks * 2048 + m * 512);
#pragma unroll
            for (int m = 0; m < 4; ++m)
#pragma unroll
                for (int n = 0; n < 4; ++n)
                    acc[m][n] = __builtin_amdgcn_mfma_f32_16x16x32_bf16(
                        bg[ks & 3][n], af[m], acc[m][n], 0, 0, 0);
        }

        // ---- epilogue: quad -> density -> online LSE ----
        const float4 cv = cv4[cw];
#pragma unroll
        for (int m = 0; m < 4; ++m) {
            float d[4];
#pragma unroll
            for (int n = 0; n < 4; ++n) {
                v4f qv = acc[m][n];
                float s = qv[0] * qv[0] + qv[1] * qv[1] + qv[2] * qv[2] + qv[3] * qv[3];
                s += __shfl_xor(s, 16);
                s += __shfl_xor(s, 32);
                const float cc = (n == 0) ? cv.x : (n == 1) ? cv.y : (n == 2) ? cv.z : cv.w;
                d[n] = cc - 128.0f * __logf(1.0f - s);
            }
            const float mt = fmaxf(fmaxf(d[0], d[1]), fmaxf(d[2], d[3]));
            const float mn = fmaxf(mrun[m], mt);
            srun[m] = srun[m] * __expf(mrun[m] - mn)
                    + __expf(d[0] - mn) + __expf(d[1] - mn)
                    + __expf(d[2] - mn) + __expf(d[3] - mn);
            mrun[m] = mn;
        }
    }
#undef LOADB

    // ---- merge 4 per-wave partials -> per-point LSE -> one atomic ----
    if (lane < 16) {
#pragma unroll
        for (int m = 0; m < 4; ++m) {
            psum[w][m][lo][0] = mrun[m];
            psum[w][m][lo][1] = srun[m];
        }
    }
    __syncthreads();
    if (t < 64) {
        const int m = t >> 4, l = t & 15;
        float M0 = psum[0][m][l][0];
        M0 = fmaxf(M0, psum[1][m][l][0]);
        M0 = fmaxf(M0, psum[2][m][l][0]);
        M0 = fmaxf(M0, psum[3][m][l][0]);
        float s = psum[0][m][l][1] * __expf(psum[0][m][l][0] - M0)
                + psum[1][m][l][1] * __expf(psum[1][m][l][0] - M0)
                + psum[2][m][l][1] * __expf(psum[2][m][l][0] - M0)
                + psum[3][m][l][1] * __expf(psum[3][m][l][0] - M0);
        const int pt = n0 + m * 16 + l;
        float local = (pt < NPTS) ? (M0 + __logf(s)) : 0.f;
        for (int off = 32; off; off >>= 1) local += __shfl_xor(local, off);
        if (t == 0) atomicAdd(out, local);
    }
}

extern "C" void kernel_launch(void* const* d_in, const int* in_sizes, int n_in,
                              void* d_out, int out_size, void* d_ws, size_t ws_size,
                              hipStream_t stream) {
    const float* X  = (const float*)d_in[0];
    const float* M  = (const float*)d_in[1];
    const float* pi = (const float*)d_in[2];
    float* out = (float*)d_out;

    char* ws = (char*)d_ws;
    __bf16* Xb   = (__bf16*)ws;                   // 1568*16384*2 = 51,380,224
    __bf16* Bt   = (__bf16*)(ws + 51380224);      // 16*16384*2   =    524,288
    float*  cvec = (float*)(ws + 51904512);       // 256 B

    const double half_p = 128.0;
    const float logSA = (float)(lgamma(half_p) - log(2.0) - half_p * log(M_PI));

    hipMemsetAsync(d_out, 0, sizeof(float), stream);
    prep_comp<<<64, 256, 0, stream>>>(M, pi, Bt, cvec, logSA);
    convert_X<<<NSTRIPE, 256, 0, stream>>>(X, Xb);
    gemm_density<<<NSTRIPE, 256, 0, stream>>>(Xb, Bt, cvec, out);
}